// Round 1
// baseline (701.636 us; speedup 1.0000x reference)
//
#include <hip/hip_runtime.h>
#include <math.h>

#define G 4
#define NN 1024
#define FF 256
#define HH 256
#define BB 32
#define LL 4

// ---------------------------------------------------------------------------
// Batched GEMM: C[g] = act(A[g]*Bm[g] + bias), row-major.
// A: M x K (stride aStride per graph), Bm: K x Nc (bStride per graph, 0 = shared),
// C: M x Nc (cStride per graph). ACT: 0=none, 1=relu, 2=tanh.
// Tiles: BM=BN=64, BK=16; 256 threads; 4x4 microtile per thread.
// ---------------------------------------------------------------------------
template <int ACT>
__global__ __launch_bounds__(256) void gemm_kernel(
    const float* __restrict__ Aall, long aStride,
    const float* __restrict__ Ball, long bStride,
    const float* __restrict__ bias,
    float* __restrict__ Call, long cStride,
    int M, int K, int Nc) {
  __shared__ __align__(16) float As[16][68];  // [k][m], pad 68 for alignment
  __shared__ __align__(16) float Bs[16][68];  // [k][n]

  const int g = blockIdx.z;
  const float* A = Aall + (long)g * aStride;
  const float* Bm = Ball + (long)g * bStride;
  float* C = Call + (long)g * cStride;

  const int m0 = blockIdx.y * 64;
  const int n0 = blockIdx.x * 64;
  const int tid = threadIdx.x;
  const int tx = tid & 15;   // column group
  const int ty = tid >> 4;   // row group

  float acc[4][4] = {};

  for (int k0 = 0; k0 < K; k0 += 16) {
    // Load A tile 64x16 -> As[k][m]
#pragma unroll
    for (int i = 0; i < 4; ++i) {
      int li = tid + i * 256;
      int r = li >> 4, c = li & 15;
      As[c][r] = A[(long)(m0 + r) * K + (k0 + c)];
    }
    // Load B tile 16x64 -> Bs[k][n] (coalesced)
#pragma unroll
    for (int i = 0; i < 4; ++i) {
      int li = tid + i * 256;
      int r = li >> 6, c = li & 63;
      Bs[r][c] = Bm[(long)(k0 + r) * Nc + (n0 + c)];
    }
    __syncthreads();

#pragma unroll
    for (int kk = 0; kk < 16; ++kk) {
      float4 av = *(const float4*)&As[kk][ty * 4];
      float4 bv = *(const float4*)&Bs[kk][tx * 4];
      float a[4] = {av.x, av.y, av.z, av.w};
      float b[4] = {bv.x, bv.y, bv.z, bv.w};
#pragma unroll
      for (int i = 0; i < 4; ++i)
#pragma unroll
        for (int j = 0; j < 4; ++j) acc[i][j] = fmaf(a[i], b[j], acc[i][j]);
    }
    __syncthreads();
  }

  // Epilogue
#pragma unroll
  for (int i = 0; i < 4; ++i) {
    float4 v;
    float* row = &C[(long)(m0 + ty * 4 + i) * Nc + (n0 + tx * 4)];
    float b0 = 0.f, b1 = 0.f, b2 = 0.f, b3 = 0.f;
    if (bias != nullptr) {
      b0 = bias[n0 + tx * 4 + 0];
      b1 = bias[n0 + tx * 4 + 1];
      b2 = bias[n0 + tx * 4 + 2];
      b3 = bias[n0 + tx * 4 + 3];
    }
    v.x = acc[i][0] + b0;
    v.y = acc[i][1] + b1;
    v.z = acc[i][2] + b2;
    v.w = acc[i][3] + b3;
    if (ACT == 1) {
      v.x = fmaxf(v.x, 0.f); v.y = fmaxf(v.y, 0.f);
      v.z = fmaxf(v.z, 0.f); v.w = fmaxf(v.w, 0.f);
    } else if (ACT == 2) {
      v.x = tanhf(v.x); v.y = tanhf(v.y);
      v.z = tanhf(v.z); v.w = tanhf(v.w);
    }
    *(float4*)row = v;
  }
}

// ---------------------------------------------------------------------------
// Mask normalization: detect bool-as-u8 vs bool-as-i32 layout, emit float mask
// [B,N] and denom[B] = max(sum(mask), 1).
// ---------------------------------------------------------------------------
__global__ __launch_bounds__(256) void mask_kernel(
    const void* __restrict__ mask_raw, float* __restrict__ fmask,
    float* __restrict__ denom) {
  const int b = blockIdx.x;
  const int t = threadIdx.x;
  const unsigned char* bytes = (const unsigned char*)mask_raw;

  __shared__ int fmt;  // 0 = u8 per element, 1 = i32 per element
  if (t == 0) {
    int any = 0;
    for (int i = 0; i < 256; ++i)
      if ((i & 3) && bytes[i]) any = 1;
    fmt = any ? 0 : 1;
  }
  __syncthreads();

  float cnt = 0.f;
  for (int n = t; n < NN; n += 256) {
    float v;
    if (fmt)
      v = ((const int*)mask_raw)[b * NN + n] ? 1.f : 0.f;
    else
      v = bytes[b * NN + n] ? 1.f : 0.f;
    fmask[b * NN + n] = v;
    cnt += v;
  }

  __shared__ float red[256];
  red[t] = cnt;
  __syncthreads();
  for (int s = 128; s > 0; s >>= 1) {
    if (t < s) red[t] += red[t + s];
    __syncthreads();
  }
  if (t == 0) denom[b] = fmaxf(red[0], 1.f);
}

// ---------------------------------------------------------------------------
// Masked mean with residual: out[b,h] = sum_n m[b,n]*(xL[g,n,h]+h0[g,n,h])/denom
// ---------------------------------------------------------------------------
__global__ __launch_bounds__(256) void mean_kernel(
    const float* __restrict__ xL, const float* __restrict__ h0,
    const float* __restrict__ fmask, const float* __restrict__ denom,
    const int* __restrict__ gidx, float* __restrict__ out) {
  const int b = blockIdx.x;
  const int h = threadIdx.x;
  const int g = gidx[b];
  const float* x = xL + (long)g * NN * HH;
  const float* r = h0 + (long)g * NN * HH;
  float s = 0.f;
  for (int n = 0; n < NN; ++n) {
    float m = fmask[b * NN + n];
    if (m != 0.f) {  // block-uniform branch: skip ~half the loads
      s += x[(long)n * HH + h] + r[(long)n * HH + h];
    }
  }
  out[b * HH + h] = s / denom[b];
}

extern "C" void kernel_launch(void* const* d_in, const int* in_sizes, int n_in,
                              void* d_out, int out_size, void* d_ws,
                              size_t ws_size, hipStream_t stream) {
  const float* batch_xs = (const float*)d_in[0];  // [G,N,F]
  const float* batch_as = (const float*)d_in[1];  // [G,N,N]
  const float* w_in = (const float*)d_in[2];      // [F,H]
  const float* b_in = (const float*)d_in[3];      // [H]
  const float* gcn_w = (const float*)d_in[4];     // [L,H,H]
  const float* gcn_b = (const float*)d_in[5];     // [L,H]
  const int* graph_idx = (const int*)d_in[6];     // [B]
  const void* cp_mask = d_in[7];                  // [B,N] bool (layout probed)
  float* out = (float*)d_out;                     // [B,H]

  // Workspace layout (floats)
  float* h0 = (float*)d_ws;              // [G,N,H] residual / layer-0 input
  float* xa = h0 + (long)G * NN * HH;    // ping
  float* xb = xa + (long)G * NN * HH;    // pong
  float* T = xb + (long)G * NN * HH;     // A@x scratch
  float* fmask = T + (long)G * NN * HH;  // [B,N]
  float* denom = fmask + (long)BB * NN;  // [B]

  // Mask normalization (independent of GEMM chain)
  mask_kernel<<<BB, 256, 0, stream>>>(cp_mask, fmask, denom);

  // Input layer: h0 = relu(X @ w_in + b_in)   [per graph]
  {
    dim3 grid(HH / 64, NN / 64, G);
    gemm_kernel<1><<<grid, 256, 0, stream>>>(
        batch_xs, (long)NN * FF, w_in, 0, b_in, h0, (long)NN * HH, NN, FF, HH);
  }

  // GCN layers
  const float* xin = h0;
  float* bufs[2] = {xa, xb};
  for (int l = 0; l < LL; ++l) {
    float* xout = bufs[l & 1];
    // T = A @ xin    (M=N=1024, K=1024, Nc=H)
    {
      dim3 grid(HH / 64, NN / 64, G);
      gemm_kernel<0><<<grid, 256, 0, stream>>>(
          batch_as, (long)NN * NN, xin, (long)NN * HH, nullptr, T,
          (long)NN * HH, NN, NN, HH);
    }
    // xout = act(T @ W_l + b_l)
    {
      dim3 grid(HH / 64, NN / 64, G);
      if (l < LL - 1)
        gemm_kernel<1><<<grid, 256, 0, stream>>>(
            T, (long)NN * HH, gcn_w + (long)l * HH * HH, 0, gcn_b + l * HH,
            xout, (long)NN * HH, NN, HH, HH);
      else
        gemm_kernel<2><<<grid, 256, 0, stream>>>(
            T, (long)NN * HH, gcn_w + (long)l * HH * HH, 0, gcn_b + l * HH,
            xout, (long)NN * HH, NN, HH, HH);
    }
    xin = xout;
  }

  // Masked mean with residual
  mean_kernel<<<BB, 256, 0, stream>>>(xin, h0, fmask, denom, graph_idx, out);
}

// Round 2
// 333.195 us; speedup vs baseline: 2.1058x; 2.1058x over previous
//
#include <hip/hip_runtime.h>
#include <math.h>

#define G 4
#define NN 1024
#define FF 256
#define HH 256
#define BB 32
#define LL 4
#define BK 32

// ---------------------------------------------------------------------------
// Tiled GEMM, 64x64 tile, 256 threads, 4x4 microtile, BK=32, register
// prefetch of the next K-tile overlapping compute.
//   C[z] = act( (A1[g] (+A2[g])) @ B[g] + bias ) (+ resid[g])
// SPLITK: blockIdx.z in [0,2G): g = z&3, k-half = z>>2; C indexed by z.
// DUAL_A: A-operand is elementwise sum of two buffers (split-K reduction).
// ACT: 0=none, 1=relu, 2=tanh(+resid).
// ---------------------------------------------------------------------------
template <int ACT, bool DUAL_A, bool SPLITK>
__global__ __launch_bounds__(256) void gemm_kernel(
    const float* __restrict__ Aall, const float* __restrict__ A2all,
    long aStride, const float* __restrict__ Ball, long bStride,
    const float* __restrict__ bias, const float* __restrict__ residAll,
    float* __restrict__ Call, long cStride, int Kb, int Kfull, int Nc) {
  __shared__ __align__(16) float As[BK][68];  // [k][m], padded
  __shared__ __align__(16) float Bs[BK][68];  // [k][n], padded

  const int z = blockIdx.z;
  const int g = SPLITK ? (z & 3) : z;
  const long koff = SPLITK ? (long)(z >> 2) * Kb : 0;

  const float* A = Aall + (long)g * aStride + koff;
  const float* A2 = DUAL_A ? (A2all + (long)g * aStride + koff) : nullptr;
  const float* Bm = Ball + (long)g * bStride + koff * Nc;
  float* C = Call + (long)z * cStride;
  const float* resid =
      (ACT == 2 && residAll) ? (residAll + (long)g * cStride) : nullptr;

  const int m0 = blockIdx.y * 64;
  const int n0 = blockIdx.x * 64;
  const int tid = threadIdx.x;
  const int tx = tid & 15, ty = tid >> 4;

  // global->reg prefetch mapping
  const int ar0 = tid >> 3;          // A rows: ar0, ar0+32
  const int ac4 = (tid & 7) * 4;     // A k-col (float4)
  const int br0 = tid >> 4;          // B rows: br0, br0+16
  const int bc4 = (tid & 15) * 4;    // B col (float4)

  float4 pa[2], pb[2];

  auto load_tile = [&](int t) {
    const long kb = (long)t * BK;
#pragma unroll
    for (int i = 0; i < 2; ++i) {
      const int arow = ar0 + i * 32;
      pa[i] = *(const float4*)&A[(long)(m0 + arow) * Kfull + kb + ac4];
      if (DUAL_A) {
        float4 q = *(const float4*)&A2[(long)(m0 + arow) * Kfull + kb + ac4];
        pa[i].x += q.x; pa[i].y += q.y; pa[i].z += q.z; pa[i].w += q.w;
      }
      const int brow = br0 + i * 16;
      pb[i] = *(const float4*)&Bm[(kb + brow) * Nc + n0 + bc4];
    }
  };
  auto store_tile = [&]() {
#pragma unroll
    for (int i = 0; i < 2; ++i) {
      const int arow = ar0 + i * 32;
      As[ac4 + 0][arow] = pa[i].x;
      As[ac4 + 1][arow] = pa[i].y;
      As[ac4 + 2][arow] = pa[i].z;
      As[ac4 + 3][arow] = pa[i].w;
      *(float4*)&Bs[br0 + i * 16][bc4] = pb[i];
    }
  };

  float acc[4][4] = {};
  const int nt = Kb / BK;
  load_tile(0);
  for (int t = 0; t < nt; ++t) {
    __syncthreads();   // previous compute done reading LDS
    store_tile();
    __syncthreads();   // LDS tile visible
    if (t + 1 < nt) load_tile(t + 1);  // overlap with compute below
#pragma unroll
    for (int kk = 0; kk < BK; ++kk) {
      float4 av = *(const float4*)&As[kk][ty * 4];
      float4 bv = *(const float4*)&Bs[kk][tx * 4];
      float a[4] = {av.x, av.y, av.z, av.w};
      float b[4] = {bv.x, bv.y, bv.z, bv.w};
#pragma unroll
      for (int i = 0; i < 4; ++i)
#pragma unroll
        for (int j = 0; j < 4; ++j) acc[i][j] = fmaf(a[i], b[j], acc[i][j]);
    }
  }

  // Epilogue
#pragma unroll
  for (int i = 0; i < 4; ++i) {
    const long mr = m0 + ty * 4 + i;
    const int nc = n0 + tx * 4;
    float4 v;
    v.x = acc[i][0]; v.y = acc[i][1]; v.z = acc[i][2]; v.w = acc[i][3];
    if (bias != nullptr) {
      v.x += bias[nc + 0]; v.y += bias[nc + 1];
      v.z += bias[nc + 2]; v.w += bias[nc + 3];
    }
    if (ACT == 1) {
      v.x = fmaxf(v.x, 0.f); v.y = fmaxf(v.y, 0.f);
      v.z = fmaxf(v.z, 0.f); v.w = fmaxf(v.w, 0.f);
    } else if (ACT == 2) {
      v.x = tanhf(v.x); v.y = tanhf(v.y);
      v.z = tanhf(v.z); v.w = tanhf(v.w);
      if (resid != nullptr) {
        float4 r = *(const float4*)&resid[mr * Nc + nc];
        v.x += r.x; v.y += r.y; v.z += r.z; v.w += r.w;
      }
    }
    *(float4*)&C[mr * Nc + nc] = v;
  }
}

// ---------------------------------------------------------------------------
// Mask normalization + out zeroing. Detects bool-as-u8 vs bool-as-i32.
// ---------------------------------------------------------------------------
__global__ __launch_bounds__(256) void mask_kernel(
    const void* __restrict__ mask_raw, float* __restrict__ fmask,
    float* __restrict__ denom, float* __restrict__ out) {
  const int b = blockIdx.x;
  const int t = threadIdx.x;
  const unsigned char* bytes = (const unsigned char*)mask_raw;

  out[b * HH + t] = 0.f;  // zero accumulator target (poisoned by harness)

  __shared__ int fmt;  // 0 = u8 per element, 1 = i32 per element
  if (t == 0) {
    int any = 0;
    for (int i = 0; i < 256; ++i)
      if ((i & 3) && bytes[i]) any = 1;
    fmt = any ? 0 : 1;
  }
  __syncthreads();

  float cnt = 0.f;
  for (int n = t; n < NN; n += 256) {
    float v;
    if (fmt)
      v = ((const int*)mask_raw)[b * NN + n] ? 1.f : 0.f;
    else
      v = bytes[b * NN + n] ? 1.f : 0.f;
    fmask[b * NN + n] = v;
    cnt += v;
  }

  __shared__ float red[256];
  red[t] = cnt;
  __syncthreads();
  for (int s = 128; s > 0; s >>= 1) {
    if (t < s) red[t] += red[t + s];
    __syncthreads();
  }
  if (t == 0) denom[b] = fmaxf(red[0], 1.f);
}

// ---------------------------------------------------------------------------
// Masked mean: out[b,h] += (1/denom_b) * sum_{n in chunk} m[b,n]*x[g_b,n,h]
// Residual is already folded into x by the final GEMM epilogue.
// Grid: B * 16 chunks of 64 nodes; 256 threads (one h each).
// ---------------------------------------------------------------------------
__global__ __launch_bounds__(256) void mean_kernel(
    const float* __restrict__ x, const float* __restrict__ fmask,
    const float* __restrict__ denom, const int* __restrict__ gidx,
    float* __restrict__ out) {
  const int b = blockIdx.x >> 4;
  const int ch = blockIdx.x & 15;
  const int h = threadIdx.x;
  const int g = gidx[b];
  const float* xg = x + (long)g * NN * HH;
  const int n0 = ch * 64;
  float s = 0.f;
  for (int n = n0; n < n0 + 64; ++n) {
    float m = fmask[b * NN + n];
    if (m != 0.f) s += xg[(long)n * HH + h];  // block-uniform branch
  }
  atomicAdd(&out[b * HH + h], s / denom[b]);
}

extern "C" void kernel_launch(void* const* d_in, const int* in_sizes, int n_in,
                              void* d_out, int out_size, void* d_ws,
                              size_t ws_size, hipStream_t stream) {
  (void)in_sizes; (void)n_in; (void)out_size; (void)ws_size;
  const float* batch_xs = (const float*)d_in[0];  // [G,N,F]
  const float* batch_as = (const float*)d_in[1];  // [G,N,N]
  const float* w_in = (const float*)d_in[2];      // [F,H]
  const float* b_in = (const float*)d_in[3];      // [H]
  const float* gcn_w = (const float*)d_in[4];     // [L,H,H]
  const float* gcn_b = (const float*)d_in[5];     // [L,H]
  const int* graph_idx = (const int*)d_in[6];     // [B]
  const void* cp_mask = d_in[7];                  // [B,N] bool
  float* out = (float*)d_out;                     // [B,H]

  const long GNH = (long)G * NN * HH;
  float* h0 = (float*)d_ws;        // [G,N,H] residual / layer-0 input
  float* x = h0 + GNH;             // [G,N,H] layer activations (reused)
  float* T = x + GNH;              // [2G,N,H] split-K partial products
  float* fmask = T + 2 * GNH;      // [B,N]
  float* denom = fmask + (long)BB * NN;  // [B]

  mask_kernel<<<BB, 256, 0, stream>>>(cp_mask, fmask, denom, out);

  // h0 = relu(X @ w_in + b_in)
  {
    dim3 grid(HH / 64, NN / 64, G);
    gemm_kernel<1, false, false><<<grid, 256, 0, stream>>>(
        batch_xs, nullptr, (long)NN * FF, w_in, 0, b_in, nullptr, h0,
        (long)NN * HH, FF, FF, HH);
  }

  const float* xin = h0;
  for (int l = 0; l < LL; ++l) {
    // T[z] = A[g][:, khalf] @ xin[g][khalf, :]  (split-K=2, grid z=2G)
    {
      dim3 grid(HH / 64, NN / 64, 2 * G);
      gemm_kernel<0, false, true><<<grid, 256, 0, stream>>>(
          batch_as, nullptr, (long)NN * NN, xin, (long)NN * HH, nullptr,
          nullptr, T, (long)NN * HH, NN / 2, NN, HH);
    }
    // x = act( (T0+T1) @ W_l + b_l ) [+ h0 on final tanh layer]
    {
      dim3 grid(HH / 64, NN / 64, G);
      const float* Wl = gcn_w + (long)l * HH * HH;
      const float* bl = gcn_b + (long)l * HH;
      if (l < LL - 1)
        gemm_kernel<1, true, false><<<grid, 256, 0, stream>>>(
            T, T + GNH, (long)NN * HH, Wl, 0, bl, nullptr, x, (long)NN * HH,
            HH, HH, HH);
      else
        gemm_kernel<2, true, false><<<grid, 256, 0, stream>>>(
            T, T + GNH, (long)NN * HH, Wl, 0, bl, h0, x, (long)NN * HH,
            HH, HH, HH);
    }
    xin = x;
  }

  mean_kernel<<<BB * 16, 256, 0, stream>>>(x, fmask, denom, graph_idx, out);
}

// Round 3
// 216.729 us; speedup vs baseline: 3.2374x; 1.5374x over previous
//
#include <hip/hip_runtime.h>
#include <math.h>

#define G 4
#define NN 1024
#define FF 256
#define HH 256
#define BB 32
#define LL 4

typedef __attribute__((ext_vector_type(8))) short short8;
typedef __attribute__((ext_vector_type(8))) unsigned short ushort8;
typedef __attribute__((ext_vector_type(4))) unsigned short ushort4v;
typedef __attribute__((ext_vector_type(4))) float floatx4;

__device__ inline unsigned short f2bf(float f) {
  union { float f; unsigned u; } x; x.f = f;
  unsigned r = x.u + 0x7fffu + ((x.u >> 16) & 1u);  // RNE
  return (unsigned short)(r >> 16);
}

// ---------------------------------------------------------------------------
// bf16 MFMA GEMM. C[z] = act(A@B + bias)(+resid), A row-major [1024 x K],
// B supplied TRANSPOSED (n-major, [256][K]-ish) so both operands are
// K-contiguous. Block tile 64x64, 4 waves of 32x32 (2x2 mfma 16x16x32 frags).
// AMODE: 0=A bf16, 1=A fp32 (convert in stage), 2=A fp32 split-K pair (sum).
// OMODE bit1: write transposed bf16 [n][m] (next layer's B-operand).
// OMODE bit4: write fp32 row-major [m][n].
// SPLITK==2: z in [0,8): g=z&3, k-half=z>>2; out32 indexed by z.
// ACT: 0 none, 1 relu, 2 tanh(+resid).
// ---------------------------------------------------------------------------
template <int ACT, int AMODE, int OMODE, int SPLITK>
__global__ __launch_bounds__(256) void mfma_gemm(
    const void* __restrict__ Aptr, long aStride, long a2Off,
    const unsigned short* __restrict__ Bt, long bStride,
    const float* __restrict__ bias, const float* __restrict__ residAll,
    float* __restrict__ out32, unsigned short* __restrict__ outT,
    int Kblk, int ldA, int ldB) {
  __shared__ __align__(16) unsigned short As[64 * 72];  // [m][k], pad 72
  __shared__ __align__(16) unsigned short Bs[64 * 72];  // [n][k], pad 72

  const int z = blockIdx.z;
  const int g = (SPLITK == 2) ? (z & 3) : z;
  const int koff = (SPLITK == 2) ? (z >> 2) * Kblk : 0;
  const int m0 = blockIdx.y * 64;
  const int n0 = blockIdx.x * 64;
  const int t = threadIdx.x;
  const int lane = t & 63;
  const int w = t >> 6;
  const int wm = w & 1, wn = w >> 1;
  const int l16 = lane & 15, quad = lane >> 4;

  const unsigned short* Bg = Bt + (long)g * bStride;

  floatx4 acc[2][2];
#pragma unroll
  for (int i = 0; i < 2; ++i)
#pragma unroll
    for (int j = 0; j < 2; ++j) acc[i][j] = (floatx4){0.f, 0.f, 0.f, 0.f};

  const int nt = Kblk / 64;
  for (int tt = 0; tt < nt; ++tt) {
    const int kb = koff + tt * 64;
    // ---- stage A tile (64 rows x 64 k) ----
#pragma unroll
    for (int i = 0; i < 2; ++i) {
      const int q = t + i * 256;
      const int row = q >> 3, c8 = q & 7;
      ushort8 v;
      if (AMODE == 0) {
        const unsigned short* Ab =
            (const unsigned short*)Aptr + (long)g * aStride;
        v = *(const ushort8*)&Ab[(long)(m0 + row) * ldA + kb + c8 * 8];
      } else {
        const float* Af = (const float*)Aptr + (long)g * aStride +
                          (long)(m0 + row) * ldA + kb + c8 * 8;
        float4 f0 = *(const float4*)Af;
        float4 f1 = *(const float4*)(Af + 4);
        if (AMODE == 2) {
          const float* A2 = Af + a2Off;
          float4 g0 = *(const float4*)A2;
          float4 g1 = *(const float4*)(A2 + 4);
          f0.x += g0.x; f0.y += g0.y; f0.z += g0.z; f0.w += g0.w;
          f1.x += g1.x; f1.y += g1.y; f1.z += g1.z; f1.w += g1.w;
        }
        v[0] = f2bf(f0.x); v[1] = f2bf(f0.y); v[2] = f2bf(f0.z);
        v[3] = f2bf(f0.w); v[4] = f2bf(f1.x); v[5] = f2bf(f1.y);
        v[6] = f2bf(f1.z); v[7] = f2bf(f1.w);
      }
      *(ushort8*)&As[row * 72 + c8 * 8] = v;
    }
    // ---- stage B^T tile (64 n-rows x 64 k) ----
#pragma unroll
    for (int i = 0; i < 2; ++i) {
      const int q = t + i * 256;
      const int row = q >> 3, c8 = q & 7;
      ushort8 v = *(const ushort8*)&Bg[(long)(n0 + row) * ldB + kb + c8 * 8];
      *(ushort8*)&Bs[row * 72 + c8 * 8] = v;
    }
    __syncthreads();
    // ---- MFMA over the 64-K tile ----
#pragma unroll
    for (int kk = 0; kk < 64; kk += 32) {
      const int ko = kk + quad * 8;
      short8 a0 = *(const short8*)&As[(wm * 32 + l16) * 72 + ko];
      short8 a1 = *(const short8*)&As[(wm * 32 + 16 + l16) * 72 + ko];
      short8 b0 = *(const short8*)&Bs[(wn * 32 + l16) * 72 + ko];
      short8 b1 = *(const short8*)&Bs[(wn * 32 + 16 + l16) * 72 + ko];
      acc[0][0] =
          __builtin_amdgcn_mfma_f32_16x16x32_bf16(a0, b0, acc[0][0], 0, 0, 0);
      acc[0][1] =
          __builtin_amdgcn_mfma_f32_16x16x32_bf16(a0, b1, acc[0][1], 0, 0, 0);
      acc[1][0] =
          __builtin_amdgcn_mfma_f32_16x16x32_bf16(a1, b0, acc[1][0], 0, 0, 0);
      acc[1][1] =
          __builtin_amdgcn_mfma_f32_16x16x32_bf16(a1, b1, acc[1][1], 0, 0, 0);
    }
    __syncthreads();
  }

  // ---- epilogue ----
  const int zc = (SPLITK == 2) ? z : g;
  float* o32 = (OMODE & 4) ? out32 + (long)zc * NN * HH : nullptr;
  const float* resid =
      (ACT == 2 && residAll) ? residAll + (long)g * NN * HH : nullptr;
  unsigned short* oT = (OMODE & 1) ? outT + (long)g * HH * NN : nullptr;
#pragma unroll
  for (int i = 0; i < 2; ++i) {
#pragma unroll
    for (int j = 0; j < 2; ++j) {
      const int n = n0 + wn * 32 + j * 16 + l16;
      const int mB = m0 + wm * 32 + i * 16 + quad * 4;
      const float bv = bias ? bias[n] : 0.f;
      float y[4];
#pragma unroll
      for (int r = 0; r < 4; ++r) {
        float v = acc[i][j][r] + bv;
        if (ACT == 1) v = fmaxf(v, 0.f);
        if (ACT == 2) {
          v = tanhf(v);
          if (resid) v += resid[(long)(mB + r) * HH + n];
        }
        y[r] = v;
        if (OMODE & 4) o32[(long)(mB + r) * HH + n] = v;
      }
      if (OMODE & 1) {
        ushort4v pv;
        pv[0] = f2bf(y[0]); pv[1] = f2bf(y[1]);
        pv[2] = f2bf(y[2]); pv[3] = f2bf(y[3]);
        *(ushort4v*)&oT[(long)n * NN + mB] = pv;  // 4 consecutive m: 8B store
      }
    }
  }
}

// ---------------------------------------------------------------------------
// Converts: batch_as fp32 -> Abf bf16; w_in / gcn_w -> transposed bf16.
// Blocks [0,2048): A (8 el/thread). Blocks [2048,3328): transposes.
// ---------------------------------------------------------------------------
__global__ __launch_bounds__(256) void conv_kernel(
    const float* __restrict__ batch_as, unsigned short* __restrict__ Abf,
    const float* __restrict__ w_in, unsigned short* __restrict__ winT,
    const float* __restrict__ gcn_w, unsigned short* __restrict__ gwT) {
  const int b = blockIdx.x;
  const int t = threadIdx.x;
  if (b < 2048) {
    const long idx = ((long)b * 256 + t) * 8;
    float4 f0 = *(const float4*)&batch_as[idx];
    float4 f1 = *(const float4*)&batch_as[idx + 4];
    ushort8 v;
    v[0] = f2bf(f0.x); v[1] = f2bf(f0.y); v[2] = f2bf(f0.z); v[3] = f2bf(f0.w);
    v[4] = f2bf(f1.x); v[5] = f2bf(f1.y); v[6] = f2bf(f1.z); v[7] = f2bf(f1.w);
    *(ushort8*)&Abf[idx] = v;
  } else {
    const int b2 = b - 2048;
    const int mat = b2 >> 8;     // 0 = w_in, 1..4 = gcn_w layers
    const int rb = b2 & 255;     // output row (= input col)
    const float* src = (mat == 0) ? w_in : gcn_w + (long)(mat - 1) * HH * HH;
    unsigned short* dst = (mat == 0) ? winT : gwT + (long)(mat - 1) * HH * HH;
    dst[rb * 256 + t] = f2bf(src[t * 256 + rb]);
  }
}

// ---------------------------------------------------------------------------
// Mask normalization + out zeroing. Detects bool-as-u8 vs bool-as-i32.
// ---------------------------------------------------------------------------
__global__ __launch_bounds__(256) void mask_kernel(
    const void* __restrict__ mask_raw, float* __restrict__ fmask,
    float* __restrict__ denom, float* __restrict__ out) {
  const int b = blockIdx.x;
  const int t = threadIdx.x;
  const unsigned char* bytes = (const unsigned char*)mask_raw;

  out[b * HH + t] = 0.f;

  __shared__ int fmt;
  if (t == 0) {
    int any = 0;
    for (int i = 0; i < 256; ++i)
      if ((i & 3) && bytes[i]) any = 1;
    fmt = any ? 0 : 1;
  }
  __syncthreads();

  float cnt = 0.f;
  for (int n = t; n < NN; n += 256) {
    float v;
    if (fmt)
      v = ((const int*)mask_raw)[b * NN + n] ? 1.f : 0.f;
    else
      v = bytes[b * NN + n] ? 1.f : 0.f;
    fmask[b * NN + n] = v;
    cnt += v;
  }

  __shared__ float red[256];
  red[t] = cnt;
  __syncthreads();
  for (int s = 128; s > 0; s >>= 1) {
    if (t < s) red[t] += red[t + s];
    __syncthreads();
  }
  if (t == 0) denom[b] = fmaxf(red[0], 1.f);
}

// ---------------------------------------------------------------------------
// Masked mean (residual already folded into x by final GEMM epilogue).
// ---------------------------------------------------------------------------
__global__ __launch_bounds__(256) void mean_kernel(
    const float* __restrict__ x, const float* __restrict__ fmask,
    const float* __restrict__ denom, const int* __restrict__ gidx,
    float* __restrict__ out) {
  const int b = blockIdx.x >> 4;
  const int ch = blockIdx.x & 15;
  const int h = threadIdx.x;
  const int g = gidx[b];
  const float* xg = x + (long)g * NN * HH;
  const int n0 = ch * 64;
  float s = 0.f;
  for (int n = n0; n < n0 + 64; ++n) {
    float m = fmask[b * NN + n];
    if (m != 0.f) s += xg[(long)n * HH + h];
  }
  atomicAdd(&out[b * HH + h], s / denom[b]);
}

extern "C" void kernel_launch(void* const* d_in, const int* in_sizes, int n_in,
                              void* d_out, int out_size, void* d_ws,
                              size_t ws_size, hipStream_t stream) {
  (void)in_sizes; (void)n_in; (void)out_size; (void)ws_size;
  const float* batch_xs = (const float*)d_in[0];
  const float* batch_as = (const float*)d_in[1];
  const float* w_in = (const float*)d_in[2];
  const float* b_in = (const float*)d_in[3];
  const float* gcn_w = (const float*)d_in[4];
  const float* gcn_b = (const float*)d_in[5];
  const int* graph_idx = (const int*)d_in[6];
  const void* cp_mask = d_in[7];
  float* out = (float*)d_out;

  char* p = (char*)d_ws;
  unsigned short* Abf = (unsigned short*)p;  p += (long)G * NN * NN * 2;
  unsigned short* winT = (unsigned short*)p; p += (long)FF * HH * 2;
  unsigned short* gwT = (unsigned short*)p;  p += (long)LL * HH * HH * 2;
  unsigned short* h0T = (unsigned short*)p;  p += (long)G * HH * NN * 2;
  unsigned short* xT = (unsigned short*)p;   p += (long)G * HH * NN * 2;
  float* h0 = (float*)p;                     p += (long)G * NN * HH * 4;
  float* T = (float*)p;                      p += 8L * NN * HH * 4;
  float* xf = (float*)p;                     p += (long)G * NN * HH * 4;
  float* fmask = (float*)p;                  p += (long)BB * NN * 4;
  float* denom = (float*)p;                  p += BB * 4;

  conv_kernel<<<3328, 256, 0, stream>>>(batch_as, Abf, w_in, winT, gcn_w, gwT);
  mask_kernel<<<BB, 256, 0, stream>>>(cp_mask, fmask, denom, out);

  // input layer: h0 (fp32) + h0T (bf16^T) = relu(X @ w_in + b_in)
  {
    dim3 grid(HH / 64, NN / 64, G);
    mfma_gemm<1, 1, 5, 1><<<grid, 256, 0, stream>>>(
        batch_xs, (long)NN * FF, 0, winT, 0, b_in, nullptr, h0, h0T,
        FF, FF, HH);
  }

  for (int l = 0; l < LL; ++l) {
    // T[z] = A[g][:,half] @ x[g][half,:]  (split-K=2, fp32 partials)
    {
      dim3 grid(HH / 64, NN / 64, 2 * G);
      mfma_gemm<0, 0, 4, 2><<<grid, 256, 0, stream>>>(
          Abf, (long)NN * NN, 0, (l == 0 ? h0T : xT), (long)HH * NN, nullptr,
          nullptr, T, nullptr, NN / 2, NN, NN);
    }
    // x = act((T0+T1) @ W_l + b_l); relu layers write xT, final writes xf+resid
    {
      dim3 grid(HH / 64, NN / 64, G);
      const unsigned short* Wl = gwT + (long)l * HH * HH;
      const float* bl = gcn_b + (long)l * HH;
      if (l < LL - 1)
        mfma_gemm<1, 2, 1, 1><<<grid, 256, 0, stream>>>(
            T, (long)NN * HH, 4L * NN * HH, Wl, 0, bl, nullptr, nullptr, xT,
            HH, HH, HH);
      else
        mfma_gemm<2, 2, 4, 1><<<grid, 256, 0, stream>>>(
            T, (long)NN * HH, 4L * NN * HH, Wl, 0, bl, h0, xf, nullptr,
            HH, HH, HH);
    }
  }

  mean_kernel<<<BB * 16, 256, 0, stream>>>(xf, fmask, denom, graph_idx, out);
}

// Round 5
// 183.765 us; speedup vs baseline: 3.8181x; 1.1794x over previous
//
#include <hip/hip_runtime.h>
#include <math.h>

#define G 4
#define NN 1024
#define FF 256
#define HH 256
#define BB 32
#define LL 4

typedef __attribute__((ext_vector_type(8))) short short8;
typedef __attribute__((ext_vector_type(8))) unsigned short ushort8;
typedef __attribute__((ext_vector_type(4))) unsigned short ushort4v;
typedef __attribute__((ext_vector_type(4))) float floatx4;

__device__ inline unsigned short f2bf(float f) {
  union { float f; unsigned u; } x; x.f = f;
  unsigned r = x.u + 0x7fffu + ((x.u >> 16) & 1u);  // RNE
  return (unsigned short)(r >> 16);
}

// ---------------------------------------------------------------------------
// Fused GCN layer: x_out = act( (A[g] @ x_in) @ W + b )  [+ resid on ACT==2]
// Block: 16 rows (m0..m0+16) x all 256 cols, graph g. 512 threads = 8 waves,
// wave w owns output cols [w*32, w*32+32) as 2 mfma 16x16x32 frags.
// Stage 1: T = A[16 x 1024] @ x[1024 x 256]; x given transposed (xT[n][k]).
// T -> LDS bf16 (C-layout -> A-layout round-trip). Stage 2: T @ W, W given
// transposed (WT[n][k]). ACT: 1 = relu -> write xTout bf16 [n][m];
// 2 = tanh + resid -> write xf fp32 [m][n].
// ---------------------------------------------------------------------------
template <int ACT>
__global__ __launch_bounds__(512) void layer_kernel(
    const unsigned short* __restrict__ Abf,   // [G][1024][1024]
    const unsigned short* __restrict__ xTin,  // [G][256][1024]
    const unsigned short* __restrict__ WT,    // [256][256]
    const float* __restrict__ bias,           // [256]
    const float* __restrict__ resid,          // [G][1024][256] fp32 (ACT==2)
    unsigned short* __restrict__ xTout,       // [G][256][1024] (ACT==1)
    float* __restrict__ xf) {                 // [G][1024][256] (ACT==2)
  __shared__ __align__(16) unsigned short As[16 * 72];
  __shared__ __align__(16) unsigned short Bs[256 * 72];
  __shared__ __align__(16) unsigned short Ts[16 * 264];

  const int g = blockIdx.y;
  const int m0 = blockIdx.x * 16;
  const int t = threadIdx.x;
  const int w = t >> 6;
  const int lane = t & 63;
  const int l16 = lane & 15, quad = lane >> 4;

  const unsigned short* Ag = Abf + (long)g * NN * NN + (long)m0 * NN;
  const unsigned short* xg = xTin + (long)g * HH * NN;

  // ---- stage 1: T = A @ x (K = 1024) ----
  floatx4 acc0 = {0.f, 0.f, 0.f, 0.f}, acc1 = {0.f, 0.f, 0.f, 0.f};
  for (int kb = 0; kb < NN; kb += 64) {
    __syncthreads();
    if (t < 128) {  // A tile: 16 x 64
      const int row = t >> 3, c8 = t & 7;
      *(ushort8*)&As[row * 72 + c8 * 8] =
          *(const ushort8*)&Ag[(long)row * NN + kb + c8 * 8];
    }
#pragma unroll
    for (int i = 0; i < 4; ++i) {  // xT tile: 256 x 64
      const int q = t + i * 512;
      const int row = q >> 3, c8 = q & 7;
      *(ushort8*)&Bs[row * 72 + c8 * 8] =
          *(const ushort8*)&xg[(long)row * NN + kb + c8 * 8];
    }
    __syncthreads();
#pragma unroll
    for (int kk = 0; kk < 64; kk += 32) {
      const int ko = kk + quad * 8;
      short8 a = *(const short8*)&As[l16 * 72 + ko];
      short8 b0 = *(const short8*)&Bs[(w * 32 + l16) * 72 + ko];
      short8 b1 = *(const short8*)&Bs[(w * 32 + 16 + l16) * 72 + ko];
      acc0 = __builtin_amdgcn_mfma_f32_16x16x32_bf16(a, b0, acc0, 0, 0, 0);
      acc1 = __builtin_amdgcn_mfma_f32_16x16x32_bf16(a, b1, acc1, 0, 0, 0);
    }
  }
  __syncthreads();  // all waves done reading Bs
  // T (C-layout: col n = l16-group, rows m = quad*4+r) -> Ts[m][n] bf16
#pragma unroll
  for (int r = 0; r < 4; ++r) {
    Ts[(quad * 4 + r) * 264 + (w * 32 + l16)] = f2bf(acc0[r]);
    Ts[(quad * 4 + r) * 264 + (w * 32 + 16 + l16)] = f2bf(acc1[r]);
  }

  // ---- stage 2: out = T @ W (K' = 256) ----
  floatx4 o0 = {0.f, 0.f, 0.f, 0.f}, o1 = {0.f, 0.f, 0.f, 0.f};
  for (int kb = 0; kb < HH; kb += 64) {
    __syncthreads();  // Ts written (first iter) / Bs free (later iters)
#pragma unroll
    for (int i = 0; i < 4; ++i) {  // WT tile: 256 x 64
      const int q = t + i * 512;
      const int row = q >> 3, c8 = q & 7;
      *(ushort8*)&Bs[row * 72 + c8 * 8] =
          *(const ushort8*)&WT[(long)row * HH + kb + c8 * 8];
    }
    __syncthreads();
#pragma unroll
    for (int kk = 0; kk < 64; kk += 32) {
      const int ko = kk + quad * 8;
      short8 a = *(const short8*)&Ts[l16 * 264 + kb + ko];
      short8 b0 = *(const short8*)&Bs[(w * 32 + l16) * 72 + ko];
      short8 b1 = *(const short8*)&Bs[(w * 32 + 16 + l16) * 72 + ko];
      o0 = __builtin_amdgcn_mfma_f32_16x16x32_bf16(a, b0, o0, 0, 0, 0);
      o1 = __builtin_amdgcn_mfma_f32_16x16x32_bf16(a, b1, o1, 0, 0, 0);
    }
  }

  // ---- epilogue ----
#pragma unroll
  for (int j = 0; j < 2; ++j) {
    const floatx4& oc = j ? o1 : o0;
    const int n = w * 32 + j * 16 + l16;
    const float bv = bias[n];
    if (ACT == 1) {
      ushort4v pv;
#pragma unroll
      for (int r = 0; r < 4; ++r) pv[r] = f2bf(fmaxf(oc[r] + bv, 0.f));
      *(ushort4v*)&xTout[(long)g * HH * NN + (long)n * NN + m0 + quad * 4] = pv;
    } else {
#pragma unroll
      for (int r = 0; r < 4; ++r) {
        const long m = m0 + quad * 4 + r;
        const float v = tanhf(oc[r] + bv) +
                        resid[(long)g * NN * HH + m * HH + n];
        xf[(long)g * NN * HH + m * HH + n] = v;
      }
    }
  }
}

// ---------------------------------------------------------------------------
// Input-layer GEMM (round-3 proven): h0 fp32 + h0T bf16 = relu(X@w_in + b).
// 64x64 tile, 4 waves of 32x32.
// ---------------------------------------------------------------------------
__global__ __launch_bounds__(256) void in_gemm(
    const float* __restrict__ X, const unsigned short* __restrict__ winT,
    const float* __restrict__ bias, float* __restrict__ h0,
    unsigned short* __restrict__ h0T) {
  __shared__ __align__(16) unsigned short As[64 * 72];
  __shared__ __align__(16) unsigned short Bs[64 * 72];

  const int g = blockIdx.z;
  const int m0 = blockIdx.y * 64;
  const int n0 = blockIdx.x * 64;
  const int t = threadIdx.x;
  const int lane = t & 63, w = t >> 6;
  const int wm = w & 1, wn = w >> 1;
  const int l16 = lane & 15, quad = lane >> 4;

  floatx4 acc[2][2];
#pragma unroll
  for (int i = 0; i < 2; ++i)
#pragma unroll
    for (int j = 0; j < 2; ++j) acc[i][j] = (floatx4){0.f, 0.f, 0.f, 0.f};

  for (int kb = 0; kb < FF; kb += 64) {
#pragma unroll
    for (int i = 0; i < 2; ++i) {
      const int q = t + i * 256;
      const int row = q >> 3, c8 = q & 7;
      const float* Af =
          X + (long)g * NN * FF + (long)(m0 + row) * FF + kb + c8 * 8;
      float4 f0 = *(const float4*)Af;
      float4 f1 = *(const float4*)(Af + 4);
      ushort8 v;
      v[0] = f2bf(f0.x); v[1] = f2bf(f0.y); v[2] = f2bf(f0.z);
      v[3] = f2bf(f0.w); v[4] = f2bf(f1.x); v[5] = f2bf(f1.y);
      v[6] = f2bf(f1.z); v[7] = f2bf(f1.w);
      *(ushort8*)&As[row * 72 + c8 * 8] = v;
      *(ushort8*)&Bs[row * 72 + c8 * 8] =
          *(const ushort8*)&winT[(long)(n0 + row) * FF + kb + c8 * 8];
    }
    __syncthreads();
#pragma unroll
    for (int kk = 0; kk < 64; kk += 32) {
      const int ko = kk + quad * 8;
      short8 a0 = *(const short8*)&As[(wm * 32 + l16) * 72 + ko];
      short8 a1 = *(const short8*)&As[(wm * 32 + 16 + l16) * 72 + ko];
      short8 b0 = *(const short8*)&Bs[(wn * 32 + l16) * 72 + ko];
      short8 b1 = *(const short8*)&Bs[(wn * 32 + 16 + l16) * 72 + ko];
      acc[0][0] = __builtin_amdgcn_mfma_f32_16x16x32_bf16(a0, b0, acc[0][0], 0, 0, 0);
      acc[0][1] = __builtin_amdgcn_mfma_f32_16x16x32_bf16(a0, b1, acc[0][1], 0, 0, 0);
      acc[1][0] = __builtin_amdgcn_mfma_f32_16x16x32_bf16(a1, b0, acc[1][0], 0, 0, 0);
      acc[1][1] = __builtin_amdgcn_mfma_f32_16x16x32_bf16(a1, b1, acc[1][1], 0, 0, 0);
    }
    __syncthreads();
  }

#pragma unroll
  for (int i = 0; i < 2; ++i) {
#pragma unroll
    for (int j = 0; j < 2; ++j) {
      const int n = n0 + wn * 32 + j * 16 + l16;
      const int mB = m0 + wm * 32 + i * 16 + quad * 4;
      const float bv = bias[n];
      ushort4v pv;
#pragma unroll
      for (int r = 0; r < 4; ++r) {
        const float v = fmaxf(acc[i][j][r] + bv, 0.f);
        h0[(long)g * NN * HH + (long)(mB + r) * HH + n] = v;
        pv[r] = f2bf(v);
      }
      *(ushort4v*)&h0T[(long)g * HH * NN + (long)n * NN + mB] = pv;
    }
  }
}

// ---------------------------------------------------------------------------
// Pre-work, one kernel.
// Blocks [0,1024):   A fp32->bf16, 16 el/thread (1024*256*16 = 4M = G*N*N).
// Blocks [1024,2304): weight transposes (w_in + 4 gcn_w layers).
// Blocks [2304,2336): mask normalization + denom + out zeroing.
// ---------------------------------------------------------------------------
__global__ __launch_bounds__(256) void pre_kernel(
    const float* __restrict__ batch_as, unsigned short* __restrict__ Abf,
    const float* __restrict__ w_in, unsigned short* __restrict__ winT,
    const float* __restrict__ gcn_w, unsigned short* __restrict__ gwT,
    const void* __restrict__ mask_raw, float* __restrict__ fmask,
    float* __restrict__ denom, float* __restrict__ out) {
  const int b = blockIdx.x;
  const int t = threadIdx.x;
  if (b < 1024) {
    const long idx = ((long)b * 256 + t) * 16;
#pragma unroll
    for (int h = 0; h < 2; ++h) {
      float4 f0 = *(const float4*)&batch_as[idx + h * 8];
      float4 f1 = *(const float4*)&batch_as[idx + h * 8 + 4];
      ushort8 v;
      v[0] = f2bf(f0.x); v[1] = f2bf(f0.y); v[2] = f2bf(f0.z);
      v[3] = f2bf(f0.w); v[4] = f2bf(f1.x); v[5] = f2bf(f1.y);
      v[6] = f2bf(f1.z); v[7] = f2bf(f1.w);
      *(ushort8*)&Abf[idx + h * 8] = v;
    }
  } else if (b < 2304) {
    const int b2 = b - 1024;
    const int mat = b2 >> 8;  // 0 = w_in, 1..4 = gcn_w
    const int rb = b2 & 255;  // output row (n), input col
    const float* src = (mat == 0) ? w_in : gcn_w + (long)(mat - 1) * HH * HH;
    unsigned short* dst = (mat == 0) ? winT : gwT + (long)(mat - 1) * HH * HH;
    dst[rb * 256 + t] = f2bf(src[t * 256 + rb]);
  } else {
    const int bb = b - 2304;
    const unsigned char* bytes = (const unsigned char*)mask_raw;
    out[bb * HH + t] = 0.f;
    __shared__ int fmt;
    if (t == 0) {
      int any = 0;
      for (int i = 0; i < 256; ++i)
        if ((i & 3) && bytes[i]) any = 1;
      fmt = any ? 0 : 1;
    }
    __syncthreads();
    float cnt = 0.f;
    for (int n = t; n < NN; n += 256) {
      float v;
      if (fmt)
        v = ((const int*)mask_raw)[bb * NN + n] ? 1.f : 0.f;
      else
        v = bytes[bb * NN + n] ? 1.f : 0.f;
      fmask[bb * NN + n] = v;
      cnt += v;
    }
    __shared__ float red[256];
    red[t] = cnt;
    __syncthreads();
    for (int s = 128; s > 0; s >>= 1) {
      if (t < s) red[t] += red[t + s];
      __syncthreads();
    }
    if (t == 0) denom[bb] = fmaxf(red[0], 1.f);
  }
}

// ---------------------------------------------------------------------------
// Masked mean (residual already folded into xf).
// ---------------------------------------------------------------------------
__global__ __launch_bounds__(256) void mean_kernel(
    const float* __restrict__ x, const float* __restrict__ fmask,
    const float* __restrict__ denom, const int* __restrict__ gidx,
    float* __restrict__ out) {
  const int b = blockIdx.x >> 4;
  const int ch = blockIdx.x & 15;
  const int h = threadIdx.x;
  const int g = gidx[b];
  const float* xg = x + (long)g * NN * HH;
  const int n0 = ch * 64;
  float s = 0.f;
  for (int n = n0; n < n0 + 64; ++n) {
    float m = fmask[b * NN + n];
    if (m != 0.f) s += xg[(long)n * HH + h];
  }
  atomicAdd(&out[b * HH + h], s / denom[b]);
}

extern "C" void kernel_launch(void* const* d_in, const int* in_sizes, int n_in,
                              void* d_out, int out_size, void* d_ws,
                              size_t ws_size, hipStream_t stream) {
  (void)in_sizes; (void)n_in; (void)out_size; (void)ws_size;
  const float* batch_xs = (const float*)d_in[0];
  const float* batch_as = (const float*)d_in[1];
  const float* w_in = (const float*)d_in[2];
  const float* b_in = (const float*)d_in[3];
  const float* gcn_w = (const float*)d_in[4];
  const float* gcn_b = (const float*)d_in[5];
  const int* graph_idx = (const int*)d_in[6];
  const void* cp_mask = d_in[7];
  float* out = (float*)d_out;

  char* p = (char*)d_ws;
  unsigned short* Abf = (unsigned short*)p;  p += (long)G * NN * NN * 2;
  unsigned short* winT = (unsigned short*)p; p += (long)FF * HH * 2;
  unsigned short* gwT = (unsigned short*)p;  p += (long)LL * HH * HH * 2;
  unsigned short* h0T = (unsigned short*)p;  p += (long)G * HH * NN * 2;
  unsigned short* xTa = (unsigned short*)p;  p += (long)G * HH * NN * 2;
  unsigned short* xTb = (unsigned short*)p;  p += (long)G * HH * NN * 2;
  float* h0 = (float*)p;                     p += (long)G * NN * HH * 4;
  float* xf = (float*)p;                     p += (long)G * NN * HH * 4;
  float* fmask = (float*)p;                  p += (long)BB * NN * 4;
  float* denom = (float*)p;                  p += BB * 4;

  pre_kernel<<<2336, 256, 0, stream>>>(batch_as, Abf, w_in, winT, gcn_w, gwT,
                                       cp_mask, fmask, denom, out);

  {
    dim3 grid(HH / 64, NN / 64, G);
    in_gemm<<<grid, 256, 0, stream>>>(batch_xs, winT, b_in, h0, h0T);
  }

  {
    dim3 grid(NN / 16, G);
    layer_kernel<1><<<grid, 512, 0, stream>>>(
        Abf, h0T, gwT + 0L * HH * HH, gcn_b + 0 * HH, nullptr, xTa, nullptr);
    layer_kernel<1><<<grid, 512, 0, stream>>>(
        Abf, xTa, gwT + 1L * HH * HH, gcn_b + 1 * HH, nullptr, xTb, nullptr);
    layer_kernel<1><<<grid, 512, 0, stream>>>(
        Abf, xTb, gwT + 2L * HH * HH, gcn_b + 2 * HH, nullptr, xTa, nullptr);
    layer_kernel<2><<<grid, 512, 0, stream>>>(
        Abf, xTa, gwT + 3L * HH * HH, gcn_b + 3 * HH, h0, nullptr, xf);
  }

  mean_kernel<<<BB * 16, 256, 0, stream>>>(xf, fmask, denom, graph_idx, out);
}

// Round 6
// 179.619 us; speedup vs baseline: 3.9062x; 1.0231x over previous
//
#include <hip/hip_runtime.h>
#include <math.h>

#define G 4
#define NN 1024
#define FF 256
#define HH 256
#define BB 32
#define LL 4

typedef __attribute__((ext_vector_type(8))) short short8;
typedef __attribute__((ext_vector_type(8))) unsigned short ushort8;
typedef __attribute__((ext_vector_type(4))) unsigned short ushort4v;
typedef __attribute__((ext_vector_type(4))) float floatx4;

__device__ inline unsigned short f2bf(float f) {
  union { float f; unsigned u; } x; x.f = f;
  unsigned r = x.u + 0x7fffu + ((x.u >> 16) & 1u);  // RNE
  return (unsigned short)(r >> 16);
}

// ---------------------------------------------------------------------------
// Unified bf16 MFMA GEMM, 64x64 tile, 256 thr (4 waves of 32x32 = 2x2
// 16x16x32 frags), BK=64, register prefetch of next K-tile over compute.
// A row-major [m][k]; B transposed [n][k] (both K-contiguous).
// AMODE: 0 = A bf16; 1 = A fp32 (convert at stage);
//        2 = A fp32 dual (A + A[a2Off]) + biasA[k] + relu, convert (fuses the
//            previous layer's split-K reduction + bias + relu).
// OMODE bits: 1 = bf16 transposed [n][m] (next g2's B operand);
//             2 = bf16 row-major [m][n]; 4 = fp32 row-major [m][n].
// SPLITK==2: z in [0,8): g=z&3, half=z>>2; fp32 out indexed by z.
// ACT: 0 none, 1 relu (applied with biasC at epilogue).
// ---------------------------------------------------------------------------
template <int ACT, int AMODE, int OMODE, int SPLITK>
__global__ __launch_bounds__(256) void gemm(
    const void* __restrict__ Aptr, long aStride, long a2Off,
    const float* __restrict__ biasA,
    const unsigned short* __restrict__ Bt, long bStride,
    const float* __restrict__ biasC,
    unsigned short* __restrict__ outT,   // OMODE&1: [g][n][m], row stride NN
    unsigned short* __restrict__ outBf,  // OMODE&2: [g][m][n], row stride HH
    float* __restrict__ outF,            // OMODE&4: [zc][m][n], row stride HH
    int Kb, int ldA, int ldB) {
  __shared__ __align__(16) unsigned short As[64 * 72];
  __shared__ __align__(16) unsigned short Bs[64 * 72];

  const int z = blockIdx.z;
  const int g = (SPLITK == 2) ? (z & 3) : z;
  const int koff = (SPLITK == 2) ? (z >> 2) * Kb : 0;
  const int m0 = blockIdx.y * 64;
  const int n0 = blockIdx.x * 64;
  const int t = threadIdx.x;
  const int lane = t & 63, w = t >> 6;
  const int wm = w & 1, wn = w >> 1;
  const int l16 = lane & 15, quad = lane >> 4;

  const unsigned short* Bg = Bt + (long)g * bStride;

  // prefetch registers
  ushort8 pa[2], pb[2];
  float4 pf[2][4];  // AMODE 1/2: [i][A-lo, A-hi, A2-lo, A2-hi]

  auto load_tile = [&](int tt) {
    const int kb = koff + tt * 64;
#pragma unroll
    for (int i = 0; i < 2; ++i) {
      const int q = t + i * 256;
      const int row = q >> 3, c8 = q & 7;
      if (AMODE == 0) {
        const unsigned short* Ab =
            (const unsigned short*)Aptr + (long)g * aStride;
        pa[i] = *(const ushort8*)&Ab[(long)(m0 + row) * ldA + kb + c8 * 8];
      } else {
        const float* Af = (const float*)Aptr + (long)g * aStride +
                          (long)(m0 + row) * ldA + kb + c8 * 8;
        pf[i][0] = *(const float4*)Af;
        pf[i][1] = *(const float4*)(Af + 4);
        if (AMODE == 2) {
          pf[i][2] = *(const float4*)(Af + a2Off);
          pf[i][3] = *(const float4*)(Af + a2Off + 4);
        }
      }
      pb[i] = *(const ushort8*)&Bg[(long)(n0 + row) * ldB + kb + c8 * 8];
    }
  };

  auto store_tile = [&](int tt) {
    const int kb = koff + tt * 64;
#pragma unroll
    for (int i = 0; i < 2; ++i) {
      const int q = t + i * 256;
      const int row = q >> 3, c8 = q & 7;
      ushort8 v;
      if (AMODE == 0) {
        v = pa[i];
      } else {
        float a[8] = {pf[i][0].x, pf[i][0].y, pf[i][0].z, pf[i][0].w,
                      pf[i][1].x, pf[i][1].y, pf[i][1].z, pf[i][1].w};
        if (AMODE == 2) {
          float a2[8] = {pf[i][2].x, pf[i][2].y, pf[i][2].z, pf[i][2].w,
                         pf[i][3].x, pf[i][3].y, pf[i][3].z, pf[i][3].w};
          float4 bb0 = *(const float4*)&biasA[kb + c8 * 8];
          float4 bb1 = *(const float4*)&biasA[kb + c8 * 8 + 4];
          float bb[8] = {bb0.x, bb0.y, bb0.z, bb0.w,
                         bb1.x, bb1.y, bb1.z, bb1.w};
#pragma unroll
          for (int j = 0; j < 8; ++j) a[j] = fmaxf(a[j] + a2[j] + bb[j], 0.f);
        }
#pragma unroll
        for (int j = 0; j < 8; ++j) v[j] = f2bf(a[j]);
      }
      *(ushort8*)&As[row * 72 + c8 * 8] = v;
      *(ushort8*)&Bs[row * 72 + c8 * 8] = pb[i];
    }
  };

  floatx4 acc[2][2];
#pragma unroll
  for (int i = 0; i < 2; ++i)
#pragma unroll
    for (int j = 0; j < 2; ++j) acc[i][j] = (floatx4){0.f, 0.f, 0.f, 0.f};

  const int nt = Kb / 64;
  load_tile(0);
  for (int tt = 0; tt < nt; ++tt) {
    __syncthreads();  // previous compute done reading LDS
    store_tile(tt);
    __syncthreads();  // tile visible
    if (tt + 1 < nt) load_tile(tt + 1);  // overlaps compute below
#pragma unroll
    for (int kk = 0; kk < 64; kk += 32) {
      const int ko = kk + quad * 8;
      short8 a0 = *(const short8*)&As[(wm * 32 + l16) * 72 + ko];
      short8 a1 = *(const short8*)&As[(wm * 32 + 16 + l16) * 72 + ko];
      short8 b0 = *(const short8*)&Bs[(wn * 32 + l16) * 72 + ko];
      short8 b1 = *(const short8*)&Bs[(wn * 32 + 16 + l16) * 72 + ko];
      acc[0][0] = __builtin_amdgcn_mfma_f32_16x16x32_bf16(a0, b0, acc[0][0], 0, 0, 0);
      acc[0][1] = __builtin_amdgcn_mfma_f32_16x16x32_bf16(a0, b1, acc[0][1], 0, 0, 0);
      acc[1][0] = __builtin_amdgcn_mfma_f32_16x16x32_bf16(a1, b0, acc[1][0], 0, 0, 0);
      acc[1][1] = __builtin_amdgcn_mfma_f32_16x16x32_bf16(a1, b1, acc[1][1], 0, 0, 0);
    }
  }

  // ---- epilogue ----
  const int zc = (SPLITK == 2) ? z : g;
#pragma unroll
  for (int i = 0; i < 2; ++i) {
#pragma unroll
    for (int j = 0; j < 2; ++j) {
      const int n = n0 + wn * 32 + j * 16 + l16;
      const int mB = m0 + wm * 32 + i * 16 + quad * 4;
      const float bv = biasC ? biasC[n] : 0.f;
      ushort4v pv;
#pragma unroll
      for (int r = 0; r < 4; ++r) {
        float v = acc[i][j][r] + bv;
        if (ACT == 1) v = fmaxf(v, 0.f);
        if (OMODE & 4) outF[(long)zc * NN * HH + (long)(mB + r) * HH + n] = v;
        if (OMODE & 3) pv[r] = f2bf(v);
        if (OMODE & 2)
          outBf[(long)g * NN * HH + (long)(mB + r) * HH + n] = pv[r];
      }
      if (OMODE & 1)
        *(ushort4v*)&outT[(long)g * HH * NN + (long)n * NN + mB] = pv;
    }
  }
}

// ---------------------------------------------------------------------------
// Pre-work: A fp32->bf16 (blocks [0,1024), 16 el/thr); weight transposes
// ([1024,2304)); mask+denom+out-zero ([2304,2336)).
// ---------------------------------------------------------------------------
__global__ __launch_bounds__(256) void pre_kernel(
    const float* __restrict__ batch_as, unsigned short* __restrict__ Abf,
    const float* __restrict__ w_in, unsigned short* __restrict__ winT,
    const float* __restrict__ gcn_w, unsigned short* __restrict__ gwT,
    const void* __restrict__ mask_raw, float* __restrict__ fmask,
    float* __restrict__ denom, float* __restrict__ out) {
  const int b = blockIdx.x;
  const int t = threadIdx.x;
  if (b < 1024) {
    const long idx = ((long)b * 256 + t) * 16;
#pragma unroll
    for (int h = 0; h < 2; ++h) {
      float4 f0 = *(const float4*)&batch_as[idx + h * 8];
      float4 f1 = *(const float4*)&batch_as[idx + h * 8 + 4];
      ushort8 v;
      v[0] = f2bf(f0.x); v[1] = f2bf(f0.y); v[2] = f2bf(f0.z);
      v[3] = f2bf(f0.w); v[4] = f2bf(f1.x); v[5] = f2bf(f1.y);
      v[6] = f2bf(f1.z); v[7] = f2bf(f1.w);
      *(ushort8*)&Abf[idx + h * 8] = v;
    }
  } else if (b < 2304) {
    const int b2 = b - 1024;
    const int mat = b2 >> 8;  // 0 = w_in, 1..4 = gcn_w
    const int rb = b2 & 255;  // output row (n), input col
    const float* src = (mat == 0) ? w_in : gcn_w + (long)(mat - 1) * HH * HH;
    unsigned short* dst = (mat == 0) ? winT : gwT + (long)(mat - 1) * HH * HH;
    dst[rb * 256 + t] = f2bf(src[t * 256 + rb]);
  } else {
    const int bb = b - 2304;
    const unsigned char* bytes = (const unsigned char*)mask_raw;
    out[bb * HH + t] = 0.f;
    __shared__ int fmt;
    if (t == 0) {
      int any = 0;
      for (int i = 0; i < 256; ++i)
        if ((i & 3) && bytes[i]) any = 1;
      fmt = any ? 0 : 1;
    }
    __syncthreads();
    float cnt = 0.f;
    for (int n = t; n < NN; n += 256) {
      float v;
      if (fmt)
        v = ((const int*)mask_raw)[bb * NN + n] ? 1.f : 0.f;
      else
        v = bytes[bb * NN + n] ? 1.f : 0.f;
      fmask[bb * NN + n] = v;
      cnt += v;
    }
    __shared__ float red[256];
    red[t] = cnt;
    __syncthreads();
    for (int s = 128; s > 0; s >>= 1) {
      if (t < s) red[t] += red[t + s];
      __syncthreads();
    }
    if (t == 0) denom[bb] = fmaxf(red[0], 1.f);
  }
}

// ---------------------------------------------------------------------------
// Masked mean with fused final activation:
// out[b,h] += (1/denom) * sum_n m[b,n] * (tanh(T0+T1+b3) + h0f)
// ---------------------------------------------------------------------------
__global__ __launch_bounds__(256) void mean_kernel(
    const float* __restrict__ T0, const float* __restrict__ T1,
    const float* __restrict__ bias3, const float* __restrict__ h0f,
    const float* __restrict__ fmask, const float* __restrict__ denom,
    const int* __restrict__ gidx, float* __restrict__ out) {
  const int b = blockIdx.x >> 4;
  const int ch = blockIdx.x & 15;
  const int h = threadIdx.x;
  const int g = gidx[b];
  const long base = (long)g * NN * HH;
  const float bv = bias3[h];
  const int n0 = ch * 64;
  float s = 0.f;
  for (int n = n0; n < n0 + 64; ++n) {
    float m = fmask[b * NN + n];
    if (m != 0.f) {  // block-uniform branch
      const long idx = base + (long)n * HH + h;
      s += tanhf(T0[idx] + T1[idx] + bv) + h0f[idx];
    }
  }
  atomicAdd(&out[b * HH + h], s / denom[b]);
}

extern "C" void kernel_launch(void* const* d_in, const int* in_sizes, int n_in,
                              void* d_out, int out_size, void* d_ws,
                              size_t ws_size, hipStream_t stream) {
  (void)in_sizes; (void)n_in; (void)out_size; (void)ws_size;
  const float* batch_xs = (const float*)d_in[0];
  const float* batch_as = (const float*)d_in[1];
  const float* w_in = (const float*)d_in[2];
  const float* b_in = (const float*)d_in[3];
  const float* gcn_w = (const float*)d_in[4];
  const float* gcn_b = (const float*)d_in[5];
  const int* graph_idx = (const int*)d_in[6];
  const void* cp_mask = d_in[7];
  float* out = (float*)d_out;

  char* p = (char*)d_ws;
  unsigned short* Abf = (unsigned short*)p;  p += (long)G * NN * NN * 2;
  unsigned short* winT = (unsigned short*)p; p += (long)FF * HH * 2;
  unsigned short* gwT = (unsigned short*)p;  p += (long)LL * HH * HH * 2;
  unsigned short* h0bf = (unsigned short*)p; p += (long)G * NN * HH * 2;
  unsigned short* yT = (unsigned short*)p;   p += (long)G * HH * NN * 2;
  float* h0f = (float*)p;                    p += (long)G * NN * HH * 4;
  float* Tsp = (float*)p;                    p += 8L * NN * HH * 4;
  float* fmask = (float*)p;                  p += (long)BB * NN * 4;
  float* denom = (float*)p;                  p += BB * 4;

  pre_kernel<<<2336, 256, 0, stream>>>(batch_as, Abf, w_in, winT, gcn_w, gwT,
                                       cp_mask, fmask, denom, out);

  // h0 = relu(X @ w_in + b_in): bf16 row-major + fp32 (residual)
  {
    dim3 grid(HH / 64, NN / 64, G);
    gemm<1, 1, 6, 1><<<grid, 256, 0, stream>>>(
        batch_xs, (long)NN * FF, 0, nullptr, winT, 0, b_in,
        nullptr, h0bf, h0f, FF, FF, FF);
  }

  for (int l = 0; l < LL; ++l) {
    // g1: yT = (x_l @ W_l)^T.  l==0: x=h0bf (bf16); l>0: x=relu(T0+T1+b_{l-1})
    {
      dim3 grid(NN / 64, NN / 64 / 4, G);  // (x: n-dim 1024/64? no)
      dim3 g1grid(HH / 64, NN / 64, G);
      if (l == 0)
        gemm<0, 0, 1, 1><<<g1grid, 256, 0, stream>>>(
            h0bf, (long)NN * HH, 0, nullptr, gwT + (long)l * HH * HH, 0,
            nullptr, yT, nullptr, nullptr, HH, HH, HH);
      else
        gemm<0, 2, 1, 1><<<g1grid, 256, 0, stream>>>(
            Tsp, (long)NN * HH, 4L * NN * HH, gcn_b + (long)(l - 1) * HH,
            gwT + (long)l * HH * HH, 0, nullptr, yT, nullptr, nullptr,
            HH, HH, HH);
    }
    // g2: Tsp[z] = A[g][:, half] @ y[g][half, :]  (split-K=2, fp32 partials)
    {
      dim3 grid(HH / 64, NN / 64, 2 * G);
      gemm<0, 0, 4, 2><<<grid, 256, 0, stream>>>(
          Abf, (long)NN * NN, 0, nullptr, yT, (long)HH * NN, nullptr,
          nullptr, nullptr, Tsp, NN / 2, NN, NN);
    }
  }

  // masked mean with fused tanh + bias + residual
  mean_kernel<<<BB * 16, 256, 0, stream>>>(
      Tsp, Tsp + 4L * NN * HH, gcn_b + 3L * HH, h0f, fmask, denom,
      graph_idx, out);
}